// Round 3
// baseline (176.935 us; speedup 1.0000x reference)
//
#include <hip/hip_runtime.h>

#define IMG_H 512
#define IMG_W 512
#define NIMG  32
#define RPW   2                      // output rows per wave
#define NWAVE 4                      // waves per block
#define ROWS_PER_BLOCK (RPW * NWAVE) // 8
#define STRIPS (IMG_H / ROWS_PER_BLOCK) // 64 strips per image
#define NBLK (NIMG * STRIPS)         // 2048 blocks

__device__ __forceinline__ float sh_up(float v, int lane) {
    float t = __shfl_up(v, 1, 64);
    return lane == 0 ? 0.f : t;
}
__device__ __forceinline__ float sh_dn(float v, int lane) {
    float t = __shfl_down(v, 1, 64);
    return lane == 63 ? 0.f : t;
}

// horizontal 7-box-sum: v[0..7] = this lane's 8 column values (vertical sums),
// halo via lane+-1 shuffles, sliding-window in registers.
__device__ __forceinline__ void hbox(const float* v, float* h, int lane) {
    float l5 = sh_up(v[5], lane), l6 = sh_up(v[6], lane), l7 = sh_up(v[7], lane);
    float r0 = sh_dn(v[0], lane), r1 = sh_dn(v[1], lane), r2 = sh_dn(v[2], lane);
    h[0] = ((l5 + l6) + (l7 + v[0])) + ((v[1] + v[2]) + v[3]);
    h[1] = h[0] - l5   + v[4];
    h[2] = h[1] - l6   + v[5];
    h[3] = h[2] - l7   + v[6];
    h[4] = h[3] - v[0] + v[7];
    h[5] = h[4] - v[1] + r0;
    h[6] = h[5] - v[2] + r1;
    h[7] = h[6] - v[3] + r2;
}

// load one row's 8 columns for this lane (zeros outside the image)
__device__ __forceinline__ void rowvals(const float* __restrict__ p, int y, float* x) {
    if ((unsigned)y < (unsigned)IMG_H) {
        const float4* q = (const float4*)(p + (size_t)y * IMG_W);
        float4 a = q[0], b = q[1];
        x[0] = a.x; x[1] = a.y; x[2] = a.z; x[3] = a.w;
        x[4] = b.x; x[5] = b.y; x[6] = b.z; x[7] = b.w;
    } else {
        #pragma unroll
        for (int k = 0; k < 8; ++k) x[k] = 0.f;
    }
}

extern "C" __global__ void __launch_bounds__(256, 8)
ssim_main(const float* __restrict__ img1, const float* __restrict__ img2,
          float* __restrict__ partials)
{
    constexpr float C1f = 1e-4f;   // (0.01)^2
    constexpr float C2f = 9e-4f;   // (0.03)^2

    const int tid  = threadIdx.x;
    const int lane = tid & 63;
    const int wv   = tid >> 6;

    // XCD-aware swizzle: 2048 blocks, 8 XCDs -> each XCD gets 4 whole images
    // (64 strips each) so vertical-halo rows re-hit that XCD's L2.
    const int bid   = blockIdx.x;
    const int xcd   = bid & 7;
    const int idx   = bid >> 3;           // 0..255
    const int img   = xcd * (NIMG / 8) + (idx >> 6);
    const int strip = idx & 63;
    const int wy0   = strip * ROWS_PER_BLOCK + wv * RPW;

    const size_t base = (size_t)img * (IMG_H * IMG_W) + (size_t)(lane << 3);
    const float* p1 = img1 + base;
    const float* p2 = img2 + base;

    // vertical running sums per column (8 cols/lane); NO raw-row ring --
    // the leaving row is re-loaded from L1/L2 (bit-exact same values).
    float s1[8], s2[8], s11[8], s22[8], s12[8];
    #pragma unroll
    for (int k = 0; k < 8; ++k) { s1[k] = s2[k] = s11[k] = s22[k] = s12[k] = 0.f; }

    // prologue: rows wy0-3 .. wy0+2
    #pragma unroll 2
    for (int j = 0; j < 6; ++j) {
        const int y = wy0 - 3 + j;
        float x1[8], x2[8];
        rowvals(p1, y, x1);
        rowvals(p2, y, x2);
        #pragma unroll
        for (int k = 0; k < 8; ++k) {
            s1[k] += x1[k]; s2[k] += x2[k];
            s11[k] = fmaf(x1[k], x1[k], s11[k]);
            s22[k] = fmaf(x2[k], x2[k], s22[k]);
            s12[k] = fmaf(x1[k], x2[k], s12[k]);
        }
    }

    float acc = 0.f;

    #pragma unroll 1
    for (int i = 0; i < RPW; ++i) {
        const int y = wy0 + i;

        // entering row y+3
        {
            float x1[8], x2[8];
            rowvals(p1, y + 3, x1);
            rowvals(p2, y + 3, x2);
            #pragma unroll
            for (int k = 0; k < 8; ++k) {
                s1[k] += x1[k]; s2[k] += x2[k];
                s11[k] = fmaf(x1[k], x1[k], s11[k]);
                s22[k] = fmaf(x2[k], x2[k], s22[k]);
                s12[k] = fmaf(x1[k], x2[k], s12[k]);
            }
        }

        // horizontal 7-sums for the 5 quantities
        float h1[8], h2[8], h11[8], h22[8], h12[8];
        hbox(s1,  h1,  lane);
        hbox(s2,  h2,  lane);
        hbox(s11, h11, lane);
        hbox(s22, h22, lane);
        hbox(s12, h12, lane);

        // SSIM formula + accumulate
        #pragma unroll
        for (int k = 0; k < 8; ++k) {
            const float mu1 = h1[k], mu2 = h2[k];
            const float mu11 = mu1 * mu1, mu22 = mu2 * mu2, mu12 = mu1 * mu2;
            const float sg1  = h11[k] - mu11;
            const float sg2  = h22[k] - mu22;
            const float sg12 = h12[k] - mu12;
            const float num = (2.f * mu12 + C1f) * (2.f * sg12 + C2f);
            const float den = (mu11 + mu22 + C1f) * (sg1 + sg2 + C2f);
            // den > 0 always (>= C1*C2 scale); fast rcp + 1 Newton step
            float r = __builtin_amdgcn_rcpf(den);
            r = r * (2.0f - den * r);
            acc = fmaf(num, r, acc);
        }

        // leaving row y-3: re-load (hits L1/L2) and subtract
        if (i < RPW - 1) {
            float x1[8], x2[8];
            rowvals(p1, y - 3, x1);
            rowvals(p2, y - 3, x2);
            #pragma unroll
            for (int k = 0; k < 8; ++k) {
                s1[k] -= x1[k]; s2[k] -= x2[k];
                s11[k] = fmaf(-x1[k], x1[k], s11[k]);
                s22[k] = fmaf(-x2[k], x2[k], s22[k]);
                s12[k] = fmaf(-x1[k], x2[k], s12[k]);
            }
        }
    }

    // block reduction: wave shuffle-reduce then LDS across 4 waves
    #pragma unroll
    for (int off = 32; off; off >>= 1) acc += __shfl_down(acc, off, 64);

    __shared__ float red[NWAVE];
    if (lane == 0) red[wv] = acc;
    __syncthreads();
    if (tid == 0) {
        partials[bid] = (red[0] + red[1]) + (red[2] + red[3]);
    }
}

extern "C" __global__ void __launch_bounds__(64)
ssim_final(const float* __restrict__ partials, float* __restrict__ out)
{
    const int lane = threadIdx.x;
    double s = 0.0;
    #pragma unroll
    for (int i = 0; i < NBLK / 64; ++i) s += (double)partials[lane + (i << 6)];
    #pragma unroll
    for (int off = 32; off; off >>= 1) s += __shfl_down(s, off, 64);
    if (lane == 0) {
        out[0] = (float)(1.0 - s / ((double)NIMG * IMG_H * IMG_W));
    }
}

extern "C" void kernel_launch(void* const* d_in, const int* in_sizes, int n_in,
                              void* d_out, int out_size, void* d_ws, size_t ws_size,
                              hipStream_t stream) {
    const float* img1 = (const float*)d_in[0];
    const float* img2 = (const float*)d_in[1];
    float* partials = (float*)d_ws;   // NBLK floats

    hipLaunchKernelGGL(ssim_main, dim3(NBLK), dim3(256), 0, stream,
                       img1, img2, partials);
    hipLaunchKernelGGL(ssim_final, dim3(1), dim3(64), 0, stream,
                       partials, (float*)d_out);
}

// Round 4
// 30.879 us; speedup vs baseline: 5.7299x; 5.7299x over previous
//
#include <hip/hip_runtime.h>

#define IMG_H 512
#define IMG_W 512
#define NIMG  32
#define RPW   2                      // output rows per wave
#define NWAVE 4                      // waves per block
#define ROWS_PER_BLOCK (RPW * NWAVE) // 8
#define STRIPS (IMG_H / ROWS_PER_BLOCK) // 64 strips per image
#define NBLK (NIMG * STRIPS)         // 2048 blocks

__device__ __forceinline__ float sh_up(float v, int lane) {
    float t = __shfl_up(v, 1, 64);
    return lane == 0 ? 0.f : t;
}
__device__ __forceinline__ float sh_dn(float v, int lane) {
    float t = __shfl_down(v, 1, 64);
    return lane == 63 ? 0.f : t;
}

// horizontal 7-box-sum: v[0..7] = this lane's 8 column values (vertical sums),
// halo via lane+-1 shuffles, sliding-window in registers.
__device__ __forceinline__ void hbox(const float* v, float* h, int lane) {
    float l5 = sh_up(v[5], lane), l6 = sh_up(v[6], lane), l7 = sh_up(v[7], lane);
    float r0 = sh_dn(v[0], lane), r1 = sh_dn(v[1], lane), r2 = sh_dn(v[2], lane);
    h[0] = ((l5 + l6) + (l7 + v[0])) + ((v[1] + v[2]) + v[3]);
    h[1] = h[0] - l5   + v[4];
    h[2] = h[1] - l6   + v[5];
    h[3] = h[2] - l7   + v[6];
    h[4] = h[3] - v[0] + v[7];
    h[5] = h[4] - v[1] + r0;
    h[6] = h[5] - v[2] + r1;
    h[7] = h[6] - v[3] + r2;
}

// load one row's 8 columns for this lane (zeros outside the image)
__device__ __forceinline__ void rowvals(const float* __restrict__ p, int y, float* x) {
    if ((unsigned)y < (unsigned)IMG_H) {
        const float4* q = (const float4*)(p + (size_t)y * IMG_W);
        float4 a = q[0], b = q[1];
        x[0] = a.x; x[1] = a.y; x[2] = a.z; x[3] = a.w;
        x[4] = b.x; x[5] = b.y; x[6] = b.z; x[7] = b.w;
    } else {
        #pragma unroll
        for (int k = 0; k < 8; ++k) x[k] = 0.f;
    }
}

extern "C" __global__ void __launch_bounds__(256, 4)
ssim_main(const float* __restrict__ img1, const float* __restrict__ img2,
          float* __restrict__ partials)
{
    constexpr float C1f = 1e-4f;   // (0.01)^2
    constexpr float C2f = 9e-4f;   // (0.03)^2

    const int tid  = threadIdx.x;
    const int lane = tid & 63;
    const int wv   = tid >> 6;

    // XCD-aware swizzle: 2048 blocks, 8 XCDs -> each XCD gets 4 whole images
    // (64 strips each) so vertical-halo rows re-hit that XCD's L2.
    const int bid   = blockIdx.x;
    const int xcd   = bid & 7;
    const int idx   = bid >> 3;           // 0..255
    const int img   = xcd * (NIMG / 8) + (idx >> 6);
    const int strip = idx & 63;
    const int wy0   = strip * ROWS_PER_BLOCK + wv * RPW;

    const size_t base = (size_t)img * (IMG_H * IMG_W) + (size_t)(lane << 3);
    const float* p1 = img1 + base;
    const float* p2 = img2 + base;

    // vertical running sums per column (8 cols/lane); NO raw-row ring --
    // the leaving row is re-loaded from L1/L2 (bit-exact same values).
    float s1[8], s2[8], s11[8], s22[8], s12[8];
    #pragma unroll
    for (int k = 0; k < 8; ++k) { s1[k] = s2[k] = s11[k] = s22[k] = s12[k] = 0.f; }

    // prologue: rows wy0-3 .. wy0+2
    #pragma unroll 2
    for (int j = 0; j < 6; ++j) {
        const int y = wy0 - 3 + j;
        float x1[8], x2[8];
        rowvals(p1, y, x1);
        rowvals(p2, y, x2);
        #pragma unroll
        for (int k = 0; k < 8; ++k) {
            s1[k] += x1[k]; s2[k] += x2[k];
            s11[k] = fmaf(x1[k], x1[k], s11[k]);
            s22[k] = fmaf(x2[k], x2[k], s22[k]);
            s12[k] = fmaf(x1[k], x2[k], s12[k]);
        }
    }

    float acc = 0.f;

    #pragma unroll 1
    for (int i = 0; i < RPW; ++i) {
        const int y = wy0 + i;

        // entering row y+3
        {
            float x1[8], x2[8];
            rowvals(p1, y + 3, x1);
            rowvals(p2, y + 3, x2);
            #pragma unroll
            for (int k = 0; k < 8; ++k) {
                s1[k] += x1[k]; s2[k] += x2[k];
                s11[k] = fmaf(x1[k], x1[k], s11[k]);
                s22[k] = fmaf(x2[k], x2[k], s22[k]);
                s12[k] = fmaf(x1[k], x2[k], s12[k]);
            }
        }

        // horizontal 7-sums for the 5 quantities
        float h1[8], h2[8], h11[8], h22[8], h12[8];
        hbox(s1,  h1,  lane);
        hbox(s2,  h2,  lane);
        hbox(s11, h11, lane);
        hbox(s22, h22, lane);
        hbox(s12, h12, lane);

        // SSIM formula + accumulate
        #pragma unroll
        for (int k = 0; k < 8; ++k) {
            const float mu1 = h1[k], mu2 = h2[k];
            const float mu11 = mu1 * mu1, mu22 = mu2 * mu2, mu12 = mu1 * mu2;
            const float sg1  = h11[k] - mu11;
            const float sg2  = h22[k] - mu22;
            const float sg12 = h12[k] - mu12;
            const float num = (2.f * mu12 + C1f) * (2.f * sg12 + C2f);
            const float den = (mu11 + mu22 + C1f) * (sg1 + sg2 + C2f);
            // den > 0 always (>= C1*C2 scale); fast rcp + 1 Newton step
            float r = __builtin_amdgcn_rcpf(den);
            r = r * (2.0f - den * r);
            acc = fmaf(num, r, acc);
        }

        // leaving row y-3: re-load (hits L1/L2) and subtract
        if (i < RPW - 1) {
            float x1[8], x2[8];
            rowvals(p1, y - 3, x1);
            rowvals(p2, y - 3, x2);
            #pragma unroll
            for (int k = 0; k < 8; ++k) {
                s1[k] -= x1[k]; s2[k] -= x2[k];
                s11[k] = fmaf(-x1[k], x1[k], s11[k]);
                s22[k] = fmaf(-x2[k], x2[k], s22[k]);
                s12[k] = fmaf(-x1[k], x2[k], s12[k]);
            }
        }
    }

    // block reduction: wave shuffle-reduce then LDS across 4 waves
    #pragma unroll
    for (int off = 32; off; off >>= 1) acc += __shfl_down(acc, off, 64);

    __shared__ float red[NWAVE];
    if (lane == 0) red[wv] = acc;
    __syncthreads();
    if (tid == 0) {
        partials[bid] = (red[0] + red[1]) + (red[2] + red[3]);
    }
}

extern "C" __global__ void __launch_bounds__(64)
ssim_final(const float* __restrict__ partials, float* __restrict__ out)
{
    const int lane = threadIdx.x;
    double s = 0.0;
    #pragma unroll
    for (int i = 0; i < NBLK / 64; ++i) s += (double)partials[lane + (i << 6)];
    #pragma unroll
    for (int off = 32; off; off >>= 1) s += __shfl_down(s, off, 64);
    if (lane == 0) {
        out[0] = (float)(1.0 - s / ((double)NIMG * IMG_H * IMG_W));
    }
}

extern "C" void kernel_launch(void* const* d_in, const int* in_sizes, int n_in,
                              void* d_out, int out_size, void* d_ws, size_t ws_size,
                              hipStream_t stream) {
    const float* img1 = (const float*)d_in[0];
    const float* img2 = (const float*)d_in[1];
    float* partials = (float*)d_ws;   // NBLK floats

    hipLaunchKernelGGL(ssim_main, dim3(NBLK), dim3(256), 0, stream,
                       img1, img2, partials);
    hipLaunchKernelGGL(ssim_final, dim3(1), dim3(64), 0, stream,
                       partials, (float*)d_out);
}